// Round 8
// baseline (140.710 us; speedup 1.0000x reference)
//
#include <hip/hip_runtime.h>

namespace {
constexpr float kLrelu = 0.2f;
constexpr float kEps   = 1e-5f;
}

typedef short bf16x8 __attribute__((ext_vector_type(8)));
typedef float f32x4  __attribute__((ext_vector_type(4)));

// LDS-only barrier: waits local ops, does NOT drain vmcnt -> global prefetch
// loads stay in flight across the barrier.
#define LDS_BARRIER() asm volatile("s_waitcnt lgkmcnt(0)\n\ts_barrier" ::: "memory")

// round-to-nearest-even f32 -> bf16 (inputs are finite)
static __device__ __forceinline__ unsigned f2bf(float x) {
  unsigned u = __float_as_uint(x);
  return (u + 0x7FFFu + ((u >> 16) & 1u)) >> 16;
}
static __device__ __forceinline__ unsigned packbf(float a, float b) {
  return f2bf(a) | (f2bf(b) << 16);
}

// Grouped conv as 64 x [256x512x2048] bf16-MFMA GEMM + per-channel stats.
// Block = (g, z-tile 64, m-tile 256), 256 threads = 4 waves, wave tile 64z x 64m.
// Software-pipelined phases (1 barrier-pair per chunk):
//   phase N: write tiles(N)+raw(N+1) | BAR | prefetch(N+2); fragreads(N);
//            gather+pack(N+1) overlapped with setprio-MFMA(N) | BAR
// Co-resident blocks run chunk order rotated by 32 (decorrelated stalls).
// Writes raw conv output into d_out in FOLD layout: out[b][z][hp*4+oy][wp*4+ox].
__global__ __launch_bounds__(256, 2) void conv_mfma(
    const float* __restrict__ input,   // [32,128,64,64]
    const float* __restrict__ weight,  // [16384, 2048]  (k = nc*16 + ky*4 + kx)
    float* __restrict__ out,           // [32,256,32,32]
    float* __restrict__ stats)         // [16384][2] (sum, sumsq)
{
  // raw patch tiles: 32 patches (16 b x 2 nc) x 64 floats, row-XOR swizzle:
  //   addr(fl) = pl*64 + ((py ^ (bl&7))<<3) + px
  __shared__ __align__(16) float raw0[32 * 64];   // 8 KB (even phases)
  __shared__ __align__(16) float raw1[32 * 64];   // 8 KB (odd phases)
  // GEMM tiles, row = 64B (32 bf16), 16B-granule XOR swizzle (gk ^ ((row>>1)&3))
  __shared__ __align__(16) char Bs[256 * 64];     // 16 KB
  __shared__ __align__(16) char As[64 * 64];      // 4 KB

  const int bid  = blockIdx.x;
  const int orig = (bid & 7) * 64 + (bid >> 3);   // XCD-chunked (512 % 8 == 0)
  const int g    = orig >> 3;
  const int zt   = (orig >> 1) & 3;
  const int mt   = orig & 1;
  const int hp = g >> 3, wp = g & 7;
  const int z0 = zt * 64;
  const int m0 = mt * 256;
  // chunk-order stagger: co-resident blocks (bid, bid+256) offset by 32 chunks
  const int off = ((bid >> 8) & 1) << 5;

  const int tid  = threadIdx.x;
  const int lane = tid & 63;
  const int w    = tid >> 6;                      // wave 0..3, m-range = m0 + w*64
  const int llo  = lane & 15, lhi = lane >> 4;

  // -------- raw staging: thread -> patch pl=tid>>3, f4=tid&7 (rows 0-3 / 4-7)
  const int pl_s = tid >> 3;
  const int f4   = tid & 7;
  const int bl_s = pl_s >> 1;
  const int ncs_s = pl_s & 1;
  const int py_s = f4 >> 1, h_s = f4 & 1;
  const float* const gsrc = input
      + ((size_t)(mt * 16 + bl_s) * 128 + ncs_s) * 4096
      + (hp * 8 + py_s) * 64 + wp * 8 + (h_s << 2);   // 2nd load: +256 floats (py+4)
  const int roffA = pl_s * 64 + ((py_s ^ (bl_s & 7)) << 3) + (h_s << 2);
  const int roffB = pl_s * 64 + (((py_s + 4) ^ (bl_s & 7)) << 3) + (h_s << 2);
  float* const rd0a = raw0 + roffA;  float* const rd0b = raw0 + roffB;
  float* const rd1a = raw1 + roffA;  float* const rd1b = raw1 + roffB;

  // -------- weight staging: rows az0=tid>>3 and az0+32; kq=tid&7 (k=kq*4..+3)
  const int az0 = tid >> 3;
  const int kq  = tid & 7;
  const float* const wsrc =
      weight + ((size_t)(g * 256 + z0 + az0)) * 2048 + kq * 4;  // 2nd: +65536
  const int aswz = (az0 >> 1) & 3;
  char* const ad0 = As + az0 * 64 + (((kq >> 1) ^ aswz) << 4) + ((kq & 1) << 3);
  char* const ad1 = ad0 + 32 * 64;

  // -------- row-gather: thread -> (bl=tid>>4, oy=(tid>>2)&3, ky=tid&3)
  const int bl_g = tid >> 4;
  const int oy_g = (tid >> 2) & 3;
  const int ky_g = tid & 3;
  const int iy   = 2 * oy_g - 1 + ky_g;
  const unsigned rowm = ((unsigned)iy < 8u) ? 0xFFFFFFFFu : 0u;
  const int iyc  = iy < 0 ? 0 : (iy > 7 ? 7 : iy);
  const int swzg = bl_g & 7;
  const int gro0 = (bl_g * 2 + 0) * 64 + ((iyc ^ swzg) << 3);
  const int gro1 = (bl_g * 2 + 1) * 64 + ((iyc ^ swzg) << 3);
  // B-write dsts: ml = bl*16+oy*4+ox, byte col = ncs*32 + ky*8
  char* bwd[2][4];
#pragma unroll
  for (int ncs = 0; ncs < 2; ++ncs)
#pragma unroll
    for (int ox = 0; ox < 4; ++ox) {
      const int ml = bl_g * 16 + oy_g * 4 + ox;
      const int gk = ncs * 2 + (ky_g >> 1);
      bwd[ncs][ox] = Bs + ml * 64 + ((gk ^ ((ml >> 1) & 3)) << 4) + ((ky_g & 1) << 3);
    }

  // -------- fragment read pointers
  const char* afp[4];
#pragma unroll
  for (int zf = 0; zf < 4; ++zf) {
    const int ar = zf * 16 + llo;
    afp[zf] = As + ar * 64 + ((lhi ^ ((ar >> 1) & 3)) << 4);
  }
  const char* bfp[4];
#pragma unroll
  for (int mf = 0; mf < 4; ++mf) {
    const int mr = w * 64 + mf * 16 + llo;
    bfp[mf] = Bs + mr * 64 + ((lhi ^ ((mr >> 1) & 3)) << 4);
  }

  f32x4 acc[4][4] = {};

  // tap selects: row[0..7] = r0.xyzw r1.xyzw; tap(ox,kx) = row[2ox-1+kx]
  uint2 ub[2][4];                 // B-frag data for the NEXT chunk (pipelined)
  uint2 aw0, aw1;                 // A data for the NEXT chunk
  auto gather = [&](const float* rw) {
#pragma unroll
    for (int ncs = 0; ncs < 2; ++ncs) {
      const int gro = ncs ? gro1 : gro0;
      const float4 r0 = *(const float4*)(rw + gro);
      const float4 r1 = *(const float4*)(rw + gro + 4);
      uint2 t;
      t.x = packbf(0.f, r0.x) & rowm;  t.y = packbf(r0.y, r0.z) & rowm;  ub[ncs][0] = t;
      t.x = packbf(r0.y, r0.z) & rowm; t.y = packbf(r0.w, r1.x) & rowm;  ub[ncs][1] = t;
      t.x = packbf(r0.w, r1.x) & rowm; t.y = packbf(r1.y, r1.z) & rowm;  ub[ncs][2] = t;
      t.x = packbf(r1.y, r1.z) & rowm; t.y = packbf(r1.w, 0.f) & rowm;   ub[ncs][3] = t;
    }
  };
  auto writeTiles = [&]() {
    *(uint2*)ad0 = aw0;
    *(uint2*)ad1 = aw1;
#pragma unroll
    for (int ncs = 0; ncs < 2; ++ncs)
#pragma unroll
      for (int ox = 0; ox < 4; ++ox) *(uint2*)bwd[ncs][ox] = ub[ncs][ox];
  };
  auto mfma16 = [&]() {
    bf16x8 bfv[4], afv[4];
#pragma unroll
    for (int mf = 0; mf < 4; ++mf) bfv[mf] = *(const bf16x8*)bfp[mf];
#pragma unroll
    for (int zf = 0; zf < 4; ++zf) afv[zf] = *(const bf16x8*)afp[zf];
    __builtin_amdgcn_s_setprio(1);
#pragma unroll
    for (int zf = 0; zf < 4; ++zf)
#pragma unroll
      for (int mf = 0; mf < 4; ++mf)
        acc[zf][mf] = __builtin_amdgcn_mfma_f32_16x16x32_bf16(afv[zf], bfv[mf], acc[zf][mf], 0, 0, 0);
    __builtin_amdgcn_s_setprio(0);
  };

  // -------- prologue: build ub/aw for chunk o0; prefetch chunk o1 -----------
  {
    const int o0 = off;
    float4 pa  = *(const float4*)(gsrc + (size_t)o0 * 8192);
    float4 pb  = *(const float4*)(gsrc + (size_t)o0 * 8192 + 256);
    float4 pwa = *(const float4*)(wsrc + o0 * 32);
    float4 pwb = *(const float4*)(wsrc + 65536 + o0 * 32);
    *(float4*)rd1a = pa;               // park chunk o0 raw in raw1
    *(float4*)rd1b = pb;
    __syncthreads();
    aw0.x = packbf(pwa.x, pwa.y); aw0.y = packbf(pwa.z, pwa.w);
    aw1.x = packbf(pwb.x, pwb.y); aw1.y = packbf(pwb.z, pwb.w);
    gather(raw1);
  }
  const int o1 = (off + 1) & 63;
  float4 rS1a = *(const float4*)(gsrc + (size_t)o1 * 8192);
  float4 rS1b = *(const float4*)(gsrc + (size_t)o1 * 8192 + 256);
  float4 wS1a = *(const float4*)(wsrc + o1 * 32);
  float4 wS1b = *(const float4*)(wsrc + 65536 + o1 * 32);
  float4 rS0a, rS0b, wS0a, wS0b;

  for (int n = 0; n < 64; n += 2) {
    // ============ even phase n: MFMA chunk o(n); pipeline o(n+1) =============
    {
      writeTiles();                          // tiles for chunk o(n)
      *(float4*)rd0a = rS1a;                 // stage raw(o(n+1)) -> raw0
      *(float4*)rd0b = rS1b;
      LDS_BARRIER();
      if (n + 2 < 64) {                      // prefetch chunk o(n+2) -> set0
        const int oc = (off + n + 2) & 63;
        rS0a = *(const float4*)(gsrc + (size_t)oc * 8192);
        rS0b = *(const float4*)(gsrc + (size_t)oc * 8192 + 256);
        wS0a = *(const float4*)(wsrc + oc * 32);
        wS0b = *(const float4*)(wsrc + 65536 + oc * 32);
      }
      // frag reads for o(n) are issued inside mfma16 (first), then gather o(n+1)
      // runs on the VALU while MFMAs execute.
      {
        bf16x8 bfv[4], afv[4];
#pragma unroll
        for (int mf = 0; mf < 4; ++mf) bfv[mf] = *(const bf16x8*)bfp[mf];
#pragma unroll
        for (int zf = 0; zf < 4; ++zf) afv[zf] = *(const bf16x8*)afp[zf];
        gather(raw0);                        // chunk o(n+1) B data
        aw0.x = packbf(wS1a.x, wS1a.y); aw0.y = packbf(wS1a.z, wS1a.w);
        aw1.x = packbf(wS1b.x, wS1b.y); aw1.y = packbf(wS1b.z, wS1b.w);
        __builtin_amdgcn_s_setprio(1);
#pragma unroll
        for (int zf = 0; zf < 4; ++zf)
#pragma unroll
          for (int mf = 0; mf < 4; ++mf)
            acc[zf][mf] = __builtin_amdgcn_mfma_f32_16x16x32_bf16(afv[zf], bfv[mf], acc[zf][mf], 0, 0, 0);
        __builtin_amdgcn_s_setprio(0);
      }
      LDS_BARRIER();
    }
    // ============ odd phase n+1: MFMA chunk o(n+1); pipeline o(n+2) ==========
    {
      writeTiles();                          // tiles for chunk o(n+1)
      if (n + 2 < 64) {                      // stage raw(o(n+2)) -> raw1
        *(float4*)rd1a = rS0a;
        *(float4*)rd1b = rS0b;
      }
      LDS_BARRIER();
      if (n + 3 < 64) {                      // prefetch chunk o(n+3) -> set1
        const int oc = (off + n + 3) & 63;
        rS1a = *(const float4*)(gsrc + (size_t)oc * 8192);
        rS1b = *(const float4*)(gsrc + (size_t)oc * 8192 + 256);
        wS1a = *(const float4*)(wsrc + oc * 32);
        wS1b = *(const float4*)(wsrc + 65536 + oc * 32);
      }
      {
        bf16x8 bfv[4], afv[4];
#pragma unroll
        for (int mf = 0; mf < 4; ++mf) bfv[mf] = *(const bf16x8*)bfp[mf];
#pragma unroll
        for (int zf = 0; zf < 4; ++zf) afv[zf] = *(const bf16x8*)afp[zf];
        if (n + 2 < 64) {
          gather(raw1);                      // chunk o(n+2) B data
          aw0.x = packbf(wS0a.x, wS0a.y); aw0.y = packbf(wS0a.z, wS0a.w);
          aw1.x = packbf(wS0b.x, wS0b.y); aw1.y = packbf(wS0b.z, wS0b.w);
        }
        __builtin_amdgcn_s_setprio(1);
#pragma unroll
        for (int zf = 0; zf < 4; ++zf)
#pragma unroll
          for (int mf = 0; mf < 4; ++mf)
            acc[zf][mf] = __builtin_amdgcn_mfma_f32_16x16x32_bf16(afv[zf], bfv[mf], acc[zf][mf], 0, 0, 0);
        __builtin_amdgcn_s_setprio(0);
      }
      LDS_BARRIER();
    }
  }

  // -------- per-channel stats (sum, sumsq) over the wave's 64 m
#pragma unroll
  for (int zf = 0; zf < 4; ++zf) {
    float s[4], ss[4];
#pragma unroll
    for (int r = 0; r < 4; ++r) {
      s[r]  = acc[zf][0][r] + acc[zf][1][r] + acc[zf][2][r] + acc[zf][3][r];
      ss[r] = acc[zf][0][r] * acc[zf][0][r] + acc[zf][1][r] * acc[zf][1][r]
            + acc[zf][2][r] * acc[zf][2][r] + acc[zf][3][r] * acc[zf][3][r];
    }
#pragma unroll
    for (int off2 = 1; off2 <= 8; off2 <<= 1) {
#pragma unroll
      for (int r = 0; r < 4; ++r) {
        s[r]  += __shfl_xor(s[r], off2);
        ss[r] += __shfl_xor(ss[r], off2);
      }
    }
    if (llo == 0) {
      const int ch = g * 256 + z0 + zf * 16 + lhi * 4;
#pragma unroll
      for (int r = 0; r < 4; ++r) {
        atomicAdd(&stats[2 * (ch + r)],     s[r]);
        atomicAdd(&stats[2 * (ch + r) + 1], ss[r]);
      }
    }
  }

  // -------- store raw conv to d_out in fold layout
#pragma unroll
  for (int zf = 0; zf < 4; ++zf) {
    const int zch = z0 + zf * 16 + lhi * 4;       // + r below
#pragma unroll
    for (int mf = 0; mf < 4; ++mf) {
      const int mm  = m0 + w * 64 + mf * 16 + llo;
      const int bb  = mm >> 4;
      const int o_y = (mm >> 2) & 3;
      const int o_x = mm & 3;
      float* op = out + (((size_t)bb * 256 + zch) * 32 + hp * 4 + o_y) * 32
                      + wp * 4 + o_x;
#pragma unroll
      for (int r = 0; r < 4; ++r) op[(size_t)r * 1024] = acc[zf][mf][r];
    }
  }
}

// Pass 2: in-place BatchNorm (batch stats) + LeakyReLU on the fold-layout buffer.
__global__ __launch_bounds__(256) void bn_lrelu(
    float* __restrict__ out,
    const float* __restrict__ stats,
    const float* __restrict__ gamma,
    const float* __restrict__ beta)
{
  size_t t = (size_t)blockIdx.x * blockDim.x + threadIdx.x;
  size_t o = t * 4;                    // float4 per thread
  int X0 = (int)(o & 31);
  int Y  = (int)((o >> 5) & 31);
  int z  = (int)((o >> 10) & 255);
  int ch = ((Y >> 2) * 8 + (X0 >> 2)) * 256 + z;  // (hp*8+wp)*256 + z
  float s  = stats[2 * ch];
  float ss = stats[2 * ch + 1];
  float mean = s * (1.f / 512.f);
  float var  = fmaf(-mean, mean, ss * (1.f / 512.f));
  float inv  = gamma[ch] * rsqrtf(var + kEps);
  float sh   = fmaf(-mean, inv, beta[ch]);
  float4 v = *(float4*)&out[o];
  float vv[4] = {v.x, v.y, v.z, v.w};
#pragma unroll
  for (int j = 0; j < 4; ++j) {
    float y = fmaf(vv[j], inv, sh);
    vv[j] = y > 0.f ? y : kLrelu * y;
  }
  *(float4*)&out[o] = make_float4(vv[0], vv[1], vv[2], vv[3]);
}

extern "C" void kernel_launch(void* const* d_in, const int* in_sizes, int n_in,
                              void* d_out, int out_size, void* d_ws, size_t ws_size,
                              hipStream_t stream) {
  const float* input  = (const float*)d_in[0];
  const float* weight = (const float*)d_in[1];
  const float* gamma  = (const float*)d_in[2];
  const float* beta   = (const float*)d_in[3];
  float* out   = (float*)d_out;
  float* stats = (float*)d_ws;  // 16384 * 2 floats = 128 KB

  (void)hipMemsetAsync(stats, 0, (size_t)16384 * 2 * sizeof(float), stream);

  conv_mfma<<<512, 256, 0, stream>>>(input, weight, out, stats);

  int n4 = out_size / 4;               // 2,097,152 float4s
  bn_lrelu<<<(n4 + 255) / 256, 256, 0, stream>>>(out, stats, gamma, beta);
}